// Round 6
// baseline (95.519 us; speedup 1.0000x reference)
//
#include <hip/hip_runtime.h>

#define BS 8192
#define D  128
#define TI 256              // i-rows per block (4 waves x 64)
#define JCHUNK 512          // j's per block chunk (16 tiles of 32)
#define NJC (BS / JCHUNK)   // 16 j-chunks (grid.y)

typedef __bf16 bf16x2 __attribute__((ext_vector_type(2)));
typedef __bf16 bf16x8 __attribute__((ext_vector_type(8)));
typedef float  f32x16 __attribute__((ext_vector_type(16)));

// ---------------------------------------------------------------------------
// prep: fp32 -> bf16 row-major copy of anchor, plus row reductions
//   a_sq[i] = ||anchor_i||^2, p_sq[j] = ||positive_j||^2,
//   pd2[i]  = ||anchor_i - positive_i||^2            (all exact fp32)
// ---------------------------------------------------------------------------
__global__ __launch_bounds__(256) void prep_kernel(
        const float* __restrict__ feats,
        __bf16* __restrict__ Abf,
        float* __restrict__ a_sq, float* __restrict__ p_sq,
        float* __restrict__ pd2)
{
    const int i = blockIdx.x * 4 + (threadIdx.x >> 6);   // 0..8191
    const int t = threadIdx.x & 63;                      // lane
    const float2 a = ((const float2*)(feats + (size_t)i * D))[t];
    const float2 p = ((const float2*)(feats + (size_t)(i + BS) * D))[t];

    bf16x2 ab; ab[0] = (__bf16)a.x; ab[1] = (__bf16)a.y;
    ((bf16x2*)(Abf + (size_t)i * D))[t] = ab;

    float sa = a.x * a.x + a.y * a.y;
    float sp = p.x * p.x + p.y * p.y;
    float d0 = a.x - p.x, d1 = a.y - p.y;
    float sd = d0 * d0 + d1 * d1;
    #pragma unroll
    for (int off = 32; off >= 1; off >>= 1) {
        sa += __shfl_xor(sa, off, 64);
        sp += __shfl_xor(sp, off, 64);
        sd += __shfl_xor(sd, off, 64);
    }
    if (t == 0) { a_sq[i] = sa; p_sq[i] = sp; pd2[i] = sd; }
}

// ---------------------------------------------------------------------------
// pack: positive rows -> MFMA-fragment-major bf16 layout.
// Ppack piece index ((tile*8 + s)*64 + lane) holds the 8 bf16 the B-operand
// lane needs at k-step s of j-tile `tile`:
//   j = tile*32 + (lane&31), k = s*16 + (lane>>5)*8 .. +8
// One block per 32-row tile; thread tid covers row r=tid>>3, k-block kb=tid&7
// (16 fp32 = 64 B contiguous read -> block reads its 16 KB tile linearly).
// ---------------------------------------------------------------------------
__global__ __launch_bounds__(256) void pack_kernel(
        const float* __restrict__ feats, __bf16* __restrict__ Ppack)
{
    const int tile = blockIdx.x;          // 0..255
    const int tid  = threadIdx.x;
    const int r    = tid >> 3;            // row within tile, 0..31
    const int kb   = tid & 7;             // k-block (= MFMA step s), 0..7

    const float4* src = (const float4*)(feats +
        (size_t)(BS + tile * 32 + r) * D + kb * 16);
    float4 x0 = src[0], x1 = src[1], x2 = src[2], x3 = src[3];

    bf16x8 lo, hi;
    lo[0] = (__bf16)x0.x; lo[1] = (__bf16)x0.y; lo[2] = (__bf16)x0.z; lo[3] = (__bf16)x0.w;
    lo[4] = (__bf16)x1.x; lo[5] = (__bf16)x1.y; lo[6] = (__bf16)x1.z; lo[7] = (__bf16)x1.w;
    hi[0] = (__bf16)x2.x; hi[1] = (__bf16)x2.y; hi[2] = (__bf16)x2.z; hi[3] = (__bf16)x2.w;
    hi[4] = (__bf16)x3.x; hi[5] = (__bf16)x3.y; hi[6] = (__bf16)x3.z; hi[7] = (__bf16)x3.w;

    bf16x8* dst = (bf16x8*)Ppack + ((size_t)tile * 8 + kb) * 64;
    dst[r]      = lo;    // half 0 lane (lane = r)
    dst[32 + r] = hi;    // half 1 lane (lane = 32 + r)
}

// ---------------------------------------------------------------------------
// max kernel, LDS-free: block = 256 i-rows x 512 j-chunk, 4 waves x 64 rows.
// A fragments (2 sets) live in registers the whole kernel. B fragments are
// loaded DIRECTLY from the fragment-major Ppack with fully coalesced 1 KB
// wave-loads (global_load_dwordx4) -> MFMA. No LDS, no barriers; the block's
// 4 waves read identical B addresses ~in lockstep, so L1 eats the reuse.
//
// acc initialized to -p_sq[col]/2, so after the K-loop acc = cross - p_sq/2
// and min_j d2 = a_sq - 2 * max_j acc  -> epilogue = one v_max per reg.
//
// mfma_f32_32x32x16_bf16 layouts (HW-verified, learn_hip m74/m101):
//   A: m = lane&31, k = (lane>>5)*8 + j
//   B: n = lane&31, k = (lane>>5)*8 + j
//   C/D: col = lane&31, row = (reg&3) + 8*(reg>>2) + 4*(lane>>5)
// ---------------------------------------------------------------------------
__global__ __launch_bounds__(256, 2) void max_kernel(
        const __bf16* __restrict__ Abf, const __bf16* __restrict__ Ppack,
        const float* __restrict__ p_sq, float* __restrict__ partmax)
{
    const int tid  = threadIdx.x;
    const int wave = tid >> 6;
    const int lane = tid & 63;
    const int l31  = lane & 31;
    const int half = lane >> 5;                 // 0 or 1

    const int i0    = blockIdx.x * TI + wave * 64;    // wave's 64 anchor rows
    const int jbase = blockIdx.y * JCHUNK;
    const int tile0 = jbase >> 5;                     // first 32-j tile

    // Two A-fragment sets: rows i0+l31 and i0+32+l31, k = s*16 + half*8 ..
    bf16x8 afA[8], afB[8];
    {
        const __bf16* aA = Abf + (size_t)(i0 + l31) * D + half * 8;
        #pragma unroll
        for (int s = 0; s < 8; ++s) {
            afA[s] = *(const bf16x8*)(aA + s * 16);
            afB[s] = *(const bf16x8*)(aA + 32 * D + s * 16);
        }
    }

    float rmaxA[16], rmaxB[16];
    #pragma unroll
    for (int r = 0; r < 16; ++r) { rmaxA[r] = -3.0e38f; rmaxB[r] = -3.0e38f; }

    // this lane's stream of B pieces: piece ((tile*8+s)*64 + lane)
    const bf16x8* bp = (const bf16x8*)Ppack + (size_t)tile0 * 8 * 64 + lane;

    #pragma unroll 2
    for (int t = 0; t < JCHUNK / 32; ++t) {
        const float ci = -0.5f * p_sq[jbase + t * 32 + l31];
        f32x16 acc0, acc1;
        #pragma unroll
        for (int r = 0; r < 16; ++r) { acc0[r] = ci; acc1[r] = ci; }

        #pragma unroll
        for (int s = 0; s < 8; ++s) {
            bf16x8 b = bp[(t * 8 + s) * 64];
            acc0 = __builtin_amdgcn_mfma_f32_32x32x16_bf16(afA[s], b, acc0,
                                                           0, 0, 0);
            acc1 = __builtin_amdgcn_mfma_f32_32x32x16_bf16(afB[s], b, acc1,
                                                           0, 0, 0);
        }
        #pragma unroll
        for (int r = 0; r < 16; ++r) {
            rmaxA[r] = fmaxf(rmaxA[r], acc0[r]);
            rmaxB[r] = fmaxf(rmaxB[r], acc1[r]);
        }
    }

    // max across the 32 columns (lanes sharing the same half)
    #pragma unroll
    for (int r = 0; r < 16; ++r) {
        float vA = rmaxA[r], vB = rmaxB[r];
        #pragma unroll
        for (int off = 1; off <= 16; off <<= 1) {
            vA = fmaxf(vA, __shfl_xor(vA, off, 64));
            vB = fmaxf(vB, __shfl_xor(vB, off, 64));
        }
        rmaxA[r] = vA; rmaxB[r] = vB;
    }
    if (l31 == 0) {
        float* dst = partmax + (size_t)blockIdx.y * BS + i0;
        #pragma unroll
        for (int r = 0; r < 16; ++r) {
            int row = (r & 3) + 8 * (r >> 2) + 4 * half;
            dst[row]      = rmaxA[r];
            dst[row + 32] = rmaxB[r];
        }
    }
}

// ---------------------------------------------------------------------------
// fin stage 1: 32 blocks x 256 threads; thread handles exactly one i.
// min_j d2 = a_sq[i] - 2 * max_c partmax[c][i]
// ---------------------------------------------------------------------------
__global__ __launch_bounds__(256) void fin1_kernel(
        const float* __restrict__ partmax, const float* __restrict__ a_sq,
        const float* __restrict__ pd2, float* __restrict__ bsum)
{
    __shared__ float ssum[4];
    const int t = threadIdx.x;
    const int i = blockIdx.x * 256 + t;

    float m = -3.0e38f;
    #pragma unroll
    for (int c = 0; c < NJC; ++c)
        m = fmaxf(m, partmax[c * BS + i]);
    float negd = sqrtf(fmaxf(fmaf(-2.0f, m, a_sq[i]), 0.0f));
    float posd = sqrtf(pd2[i]);
    float sum = fmaxf(posd - negd + 1.0f, 0.0f);

    #pragma unroll
    for (int off = 32; off >= 1; off >>= 1) sum += __shfl_xor(sum, off, 64);
    if ((t & 63) == 0) ssum[t >> 6] = sum;
    __syncthreads();
    if (t == 0)
        bsum[blockIdx.x] = ssum[0] + ssum[1] + ssum[2] + ssum[3];
}

// fin stage 2: one wave sums the 32 block partials.
__global__ __launch_bounds__(64) void fin2_kernel(
        const float* __restrict__ bsum, float* __restrict__ out)
{
    const int t = threadIdx.x;
    float v = (t < 32) ? bsum[t] : 0.0f;
    #pragma unroll
    for (int off = 32; off >= 1; off >>= 1) v += __shfl_xor(v, off, 64);
    if (t == 0) out[0] = v / (float)BS;
}

// ---------------------------------------------------------------------------
extern "C" void kernel_launch(void* const* d_in, const int* in_sizes, int n_in,
                              void* d_out, int out_size, void* d_ws,
                              size_t ws_size, hipStream_t stream)
{
    const float* feats = (const float*)d_in[0];

    char* ws = (char*)d_ws;
    __bf16* Abf   = (__bf16*)ws;  ws += (size_t)BS * D * 2;   // 2 MB
    __bf16* Ppack = (__bf16*)ws;  ws += (size_t)BS * D * 2;   // 2 MB
    float* a_sq   = (float*)ws;   ws += (size_t)BS * 4;
    float* p_sq   = (float*)ws;   ws += (size_t)BS * 4;
    float* pd2    = (float*)ws;   ws += (size_t)BS * 4;
    float* partmax = (float*)ws;  ws += (size_t)NJC * BS * 4; // 512 KB
    float* bsum   = (float*)ws;   ws += 32 * 4;

    prep_kernel<<<BS / 4, 256, 0, stream>>>(feats, Abf, a_sq, p_sq, pd2);
    pack_kernel<<<BS / 32, 256, 0, stream>>>(feats, Ppack);
    dim3 grid(BS / TI, NJC);
    max_kernel<<<grid, 256, 0, stream>>>(Abf, Ppack, p_sq, partmax);
    fin1_kernel<<<BS / 256, 256, 0, stream>>>(partmax, a_sq, pd2, bsum);
    fin2_kernel<<<1, 64, 0, stream>>>(bsum, (float*)d_out);
}